// Round 6
// baseline (81.153 us; speedup 1.0000x reference)
//
#include <hip/hip_runtime.h>

// TaskAlignedAssigner (YOLO TAL) for bs=32, A=8400, M=32, C=80, K=13.
// Outputs (concat, float32): labels [b,A], boxes [b,A,4], scores [b,A,80], fg [b,A].
// 2-kernel design: kA (one block per batch, all claim-resolution in LDS) ->
// k_out (streaming output writer). No workspace zero-init kernel needed:
// kA writes d_norm/d_info densely every call.

#define BS 32
#define A_N 8400
#define M_N 32
#define C_N 80
#define TOPK 13
#define EPSF 1e-9f
#define NSLOT (M_N * TOPK)     // 416 candidate slots per batch

__device__ __forceinline__ float iou_f(float4 g, float4 p, float agt, float apd) {
    float lx = fmaxf(g.x, p.x), ly = fmaxf(g.y, p.y);
    float rx = fminf(g.z, p.z), ry = fminf(g.w, p.w);
    float w = fmaxf(rx - lx, 0.f), h = fmaxf(ry - ly, 0.f);
    float inter = w * h;
    return inter / (agt + apd - inter + EPSF);
}

__device__ __forceinline__ unsigned long long umax64(unsigned long long a, unsigned long long b) {
    return a > b ? a : b;
}

// One block per batch b. 16 waves x 2 gts: per-gt top-13 (analytic candidate
// rectangles, butterfly argmax over packed u64 keys == jax.lax.top_k tie
// order, zero-fill at lowest global indices). Claims counted in LDS; multi
// claims resolved in-block (first-max over raw IoUs, all M); pos_align/pos_ov
// in LDS; emits dense d_norm[b,a] + d_info[b,a] (bit31 fg, bits8-15 m, bits0-7 label).
__global__ __launch_bounds__(1024) void kA_assign(
    const float* __restrict__ pd, const float* __restrict__ score,
    const int* __restrict__ labels, const float* __restrict__ gt,
    const float* __restrict__ maskgt,
    float* __restrict__ d_norm, unsigned* __restrict__ d_info)
{
    __shared__ unsigned s_cnt[A_N];          // 33.6 KB claim counts
    __shared__ int   s_sa[NSLOT];            // slot -> anchor (-1 empty)
    __shared__ float s_sm[NSLOT];            // slot -> metric
    __shared__ float s_so[NSLOT];            // slot -> iou
    __shared__ unsigned s_dd[(A_N + 31) / 32]; // multi dedupe bitmap
    __shared__ float s_pal[M_N], s_pov[M_N];
    __shared__ float4 s_gt[M_N];
    __shared__ int s_lb[M_N];
    __shared__ int s_ma[256], s_mm[256];     // multi table
    __shared__ float s_mal[256], s_mov[256];
    __shared__ int s_mc;

    const int b = blockIdx.x;
    const int t = threadIdx.x;
    const int wave = t >> 6, lane = t & 63;
    const size_t base = (size_t)b * A_N;

    // Phase 0: init LDS + dense global defaults.
    for (int i = t; i < A_N; i += 1024) s_cnt[i] = 0u;
    for (int i = t; i < NSLOT; i += 1024) s_sa[i] = -1;
    for (int i = t; i < (A_N + 31) / 32; i += 1024) s_dd[i] = 0u;
    if (t < M_N) {
        s_gt[t] = ((const float4*)gt)[b * M_N + t];
        s_lb[t] = labels[b * M_N + t];
        s_pal[t] = 0.f; s_pov[t] = 0.f;
    }
    if (t == 0) s_mc = 0;
    for (int i = t; i < A_N; i += 1024) { d_norm[base + i] = 0.f; d_info[base + i] = 0u; }
    __syncthreads();

    const float4* pdb = (const float4*)pd + base;

    // Phase 1: per-gt top-13 + LDS claims. Wave w handles m = 2w, 2w+1.
    for (int it = 0; it < 2; ++it) {
        const int m = wave * 2 + it;
        if (maskgt[b * M_N + m] <= 0.f) continue;   // masked -> slots stay -1

        const float4 g = s_gt[m];
        const float agt = (g.z - g.x) * (g.w - g.y);
        const float* scb = score + base * C_N + s_lb[m];

        // Analytic candidate ranges, fixed up with the EXACT predicate
        // ((i+0.5f)*s vs edge, strict) so membership is bit-exact.
        int il0, nx0, jl0, ny0, il1, nx1, jl1, ny1, il2, nx2, jl2, ny2;
        int c0, c1, c2;
        {
#define RANGE(sv, nv, lo_out, cnt_out, e_lo, e_hi)                         \
            {                                                              \
                int lo = (int)floorf(e_lo / sv - 0.5f) - 1; lo = max(lo, 0); \
                while (lo < nv && !(((float)lo + 0.5f) * sv > e_lo)) ++lo; \
                int hi = (int)ceilf(e_hi / sv - 0.5f) + 1; hi = min(hi, nv-1); \
                while (hi >= 0 && !(((float)hi + 0.5f) * sv < e_hi)) --hi; \
                lo_out = lo; cnt_out = max(hi - lo + 1, 0);                \
            }
            RANGE(8.f, 80, il0, nx0, g.x, g.z) RANGE(8.f, 80, jl0, ny0, g.y, g.w)
            RANGE(16.f, 40, il1, nx1, g.x, g.z) RANGE(16.f, 40, jl1, ny1, g.y, g.w)
            RANGE(32.f, 20, il2, nx2, g.x, g.z) RANGE(32.f, 20, jl2, ny2, g.y, g.w)
#undef RANGE
            c0 = nx0 * ny0; c1 = nx1 * ny1; c2 = nx2 * ny2;
        }
        const int T = c0 + c1 + c2;          // <= 305 for wh<=120

        unsigned long long keys[6];
        #pragma unroll
        for (int r = 0; r < 6; ++r) {
            keys[r] = 0ull;
            const int idx = r * 64 + lane;
            if (idx < T) {
                int q, n, gbase, il, jl, nx;
                if (idx < c0)           { q = idx;           n = 80; gbase = 0;    il = il0; jl = jl0; nx = nx0; }
                else if (idx < c0 + c1) { q = idx - c0;      n = 40; gbase = 6400; il = il1; jl = jl1; nx = nx1; }
                else                    { q = idx - c0 - c1; n = 20; gbase = 8000; il = il2; jl = jl2; nx = nx2; }
                const int row = q / nx, col = q - row * nx;
                const int a = gbase + (jl + row) * n + (il + col);
                float4 p = pdb[a];
                float apd = (p.z - p.x) * (p.w - p.y);
                float iou = iou_f(g, p, agt, apd);
                float sv = scb[(size_t)a * C_N];
                float i2 = iou * iou;
                float met = sv * i2 * i2 * i2;
                if (met > 0.f)
                    keys[r] = ((unsigned long long)__float_as_uint(met) << 32)
                            | (unsigned)(~(unsigned)a);
            }
        }

        // 13 butterfly argmax passes (keys unique; 0 = empty).
        unsigned long long pick = 0ull;
        for (int k = 0; k < TOPK; ++k) {
            unsigned long long mx = 0ull;
            #pragma unroll
            for (int r = 0; r < 6; ++r) mx = umax64(mx, keys[r]);
            #pragma unroll
            for (int s = 32; s > 0; s >>= 1)
                mx = umax64(mx, (unsigned long long)__shfl_xor((long long)mx, s));
            if (mx == 0ull) break;           // uniform across wave
            if (lane == k) pick = mx;
            #pragma unroll
            for (int r = 0; r < 6; ++r) if (keys[r] == mx) keys[r] = 0ull;
        }

        // Positive-pick claims (lanes 0..npos-1).
        if (lane < TOPK && pick) {
            const int a = (int)(~(unsigned)(pick & 0xFFFFFFFFu));
            const float v = __uint_as_float((unsigned)(pick >> 32));
            float4 p = pdb[a];
            float apd = (p.z - p.x) * (p.w - p.y);
            const int slot = m * TOPK + lane;
            s_sa[slot] = a; s_sm[slot] = v; s_so[slot] = iou_f(g, p, agt, apd);
            atomicAdd(&s_cnt[a], 1u);
        }

        const int npos = __popcll(__ballot(pick != 0ull));
        const int nfill = TOPK - npos;
        if (nfill > 0) {
            // top_k fills remaining slots with metric-0 entries at the LOWEST
            // global indices; nfill>0 => npos<=12 => fill indices < 25.
            bool ing = false; float iou = 0.f, met = 0.f;
            if (lane < 32) {
                const float cx = ((float)lane + 0.5f) * 8.f, cy = 4.0f;
                ing = (cx > g.x) && (cy > g.y) && (cx < g.z) && (cy < g.w);
                if (ing) {
                    float4 p = pdb[lane];
                    float apd = (p.z - p.x) * (p.w - p.y);
                    iou = iou_f(g, p, agt, apd);
                    float i2 = iou * iou;
                    met = scb[(size_t)lane * C_N] * i2 * i2 * i2;
                }
            }
            const bool z = (lane < 32) && !(met > 0.f);
            const unsigned long long zm = __ballot(z);
            const int zb = __popcll(zm & ((1ull << lane) - 1ull));
            if (z && zb < nfill && ing) {    // picked by top_k AND in-gts
                const int slot = m * TOPK + npos + zb;
                s_sa[slot] = lane; s_sm[slot] = 0.f; s_so[slot] = iou;
                atomicAdd(&s_cnt[lane], 1u); // align contribution is 0
            }
            // rejected fill slots stay -1 (pre-initialized)
        }
    }
    __syncthreads();

    // Phase 2: survivors feed pos_*; multi anchors resolved once (dedupe).
    for (int i = t; i < NSLOT; i += 1024) {
        const int a = s_sa[i];
        if (a < 0) continue;
        if (s_cnt[a] == 1u) {
            const int m = i / TOPK;
            atomicMax((int*)&s_pal[m], __float_as_int(s_sm[i]));
            atomicMax((int*)&s_pov[m], __float_as_int(s_so[i]));
        } else {
            const unsigned bit = 1u << (a & 31);
            const unsigned old = atomicOr(&s_dd[a >> 5], bit);
            if (!(old & bit)) {              // owner resolves this anchor
                float4 p = pdb[a];
                float apd = (p.z - p.x) * (p.w - p.y);
                float best = -1.f; int bmx = 0;
                #pragma unroll
                for (int mm = 0; mm < M_N; ++mm) {
                    float4 gg = s_gt[mm];
                    float agt = (gg.z - gg.x) * (gg.w - gg.y);
                    float iou = iou_f(gg, p, agt, apd);
                    if (iou > best) { best = iou; bmx = mm; }  // first max
                }
                const float sv = score[(base + a) * C_N + s_lb[bmx]];
                const float b2 = best * best;
                const float al = sv * b2 * b2 * b2;  // raw metric (no in_gts)
                const int s = atomicAdd(&s_mc, 1);
                s_ma[s] = a; s_mm[s] = bmx; s_mal[s] = al; s_mov[s] = best;
                atomicMax((int*)&s_pal[bmx], __float_as_int(al));
                atomicMax((int*)&s_pov[bmx], __float_as_int(best));
            }
        }
    }
    __syncthreads();

    // Phase 3: scattered overrides for fg anchors.
    for (int i = t; i < NSLOT; i += 1024) {
        const int a = s_sa[i];
        if (a < 0 || s_cnt[a] != 1u) continue;
        const int m = i / TOPK;
        int l = s_lb[m]; if (l < 0) l = 0;
        d_norm[base + a] = s_sm[i] * s_pov[m] / (s_pal[m] + EPSF);
        d_info[base + a] = 0x80000000u | ((unsigned)m << 8) | (unsigned)l;
    }
    const int nm = s_mc;
    for (int i = t; i < nm; i += 1024) {
        const int a = s_ma[i], m = s_mm[i];
        int l = s_lb[m]; if (l < 0) l = 0;
        d_norm[base + a] = s_mal[i] * s_pov[m] / (s_pal[m] + EPSF);
        d_info[base + a] = 0x80000000u | ((unsigned)m << 8) | (unsigned)l;
    }
}

// Streaming output writer. Reads dense d_info/d_norm, writes all outputs
// fully coalesced (score rows block-cooperatively as float4).
__global__ __launch_bounds__(256) void k_out(
    const int* __restrict__ labels, const float* __restrict__ gt,
    const float* __restrict__ d_norm, const unsigned* __restrict__ d_info,
    float* __restrict__ out)
{
    __shared__ float4 s_gt[M_N];
    __shared__ int s_l0;
    __shared__ int s_L[256];
    __shared__ float s_n[256];
    const int b = blockIdx.y;
    const int a0 = blockIdx.x * 256;
    const int t = threadIdx.x;
    const int a = a0 + t;
    if (t < M_N) s_gt[t] = ((const float4*)gt)[b * M_N + t];
    if (t == 0) { int l = labels[b * M_N]; s_l0 = (l < 0) ? 0 : l; }
    __syncthreads();

    float* out_lbl = out;
    float* out_box = out + (size_t)BS * A_N;
    float* out_sc  = out + (size_t)BS * A_N * 5;
    float* out_fg  = out + (size_t)BS * A_N * (5 + C_N);

    int L = -1; float nv = 0.f;
    if (a < A_N) {
        const size_t off = (size_t)b * A_N + a;
        const unsigned info = d_info[off];
        const int fg = (int)(info >> 31);
        const int m = fg ? (int)((info >> 8) & 255u) : 0;
        const int l = fg ? (int)(info & 255u) : s_l0;
        if (fg) { nv = d_norm[off]; L = l; }
        out_lbl[off] = (float)l;
        ((float4*)out_box)[off] = s_gt[m];
        out_fg[off] = fg ? 1.f : 0.f;
    }
    s_L[t] = L; s_n[t] = nv;
    __syncthreads();

    const int nA = min(256, A_N - a0);
    float4* dst = (float4*)(out_sc + ((size_t)b * A_N + a0) * C_N);
    const int total = nA * (C_N / 4);
    for (int i = t; i < total; i += 256) {
        const int al = i / (C_N / 4);
        const int c4 = (i % (C_N / 4)) * 4;
        const int Lv = s_L[al];
        float4 v = make_float4(0.f, 0.f, 0.f, 0.f);
        if (Lv >= c4 && Lv < c4 + 4) ((float*)&v)[Lv - c4] = s_n[al];
        dst[i] = v;
    }
}

extern "C" void kernel_launch(void* const* d_in, const int* in_sizes, int n_in,
                              void* d_out, int out_size, void* d_ws, size_t ws_size,
                              hipStream_t stream) {
    const float* pd      = (const float*)d_in[0];
    const float* score   = (const float*)d_in[1];
    const int*   labels  = (const int*)d_in[3];
    const float* gt      = (const float*)d_in[4];
    const float* maskgt  = (const float*)d_in[5];
    float* out = (float*)d_out;

    float*    d_norm = (float*)d_ws;
    unsigned* d_info = (unsigned*)(d_norm + (size_t)BS * A_N);
    (void)ws_size; (void)in_sizes; (void)n_in;

    kA_assign<<<BS, 1024, 0, stream>>>(pd, score, labels, gt, maskgt, d_norm, d_info);
    k_out<<<dim3((A_N + 255) / 256, BS), 256, 0, stream>>>(labels, gt, d_norm, d_info, out);
}

// Round 8
// 72.206 us; speedup vs baseline: 1.1239x; 1.1239x over previous
//
#include <hip/hip_runtime.h>

// TaskAlignedAssigner (YOLO TAL) for bs=32, A=8400, M=32, C=80, K=13.
// Outputs (concat, float32): labels [b,A], boxes [b,A,4], scores [b,A,80], fg [b,A].
// 3-kernel design, no global atomics, no zero-init kernel:
//   kA_topk   : 256 blocks, one WAVE per gt -> 13 compact candidate slots/gt
//   kB_resolve: 32 blocks, one per batch -> LDS claim counting + multi-gt
//               resolution + pos maxima -> dense d_norm/d_info
//   k_out     : streaming output writer (fully coalesced)

#define BS 32
#define A_N 8400
#define M_N 32
#define C_N 80
#define TOPK 13
#define EPSF 1e-9f
#define NSLOT (M_N * TOPK)     // 416 slots per batch

__device__ __forceinline__ float iou_f(float4 g, float4 p, float agt, float apd) {
    float lx = fmaxf(g.x, p.x), ly = fmaxf(g.y, p.y);
    float rx = fminf(g.z, p.z), ry = fminf(g.w, p.w);
    float w = fmaxf(rx - lx, 0.f), h = fmaxf(ry - ly, 0.f);
    float inter = w * h;
    return inter / (agt + apd - inter + EPSF);
}

__device__ __forceinline__ unsigned long long umax64(unsigned long long a, unsigned long long b) {
    return a > b ? a : b;
}

// One WAVE per (b,m). Candidate set = 3 analytic grid rectangles (exact via
// strict-compare fixup). Top-13 via butterfly argmax over packed u64 keys
// (value desc, index asc == jax.lax.top_k tie order), then zero-fill picks at
// lowest global indices. Each of the 13 slots has exactly ONE writer lane;
// all __shfl reads are executed by all 64 lanes (no shfl-from-inactive-lane).
__global__ __launch_bounds__(256) void kA_topk(
    const float* __restrict__ pd, const float* __restrict__ score,
    const int* __restrict__ labels, const float* __restrict__ gt,
    const float* __restrict__ maskgt,
    int* __restrict__ cand_idx, float* __restrict__ cand_met,
    float* __restrict__ cand_ov)
{
    const int wave = threadIdx.x >> 6;
    const int lane = threadIdx.x & 63;
    const int bm = blockIdx.x * 4 + wave;
    const int b = bm >> 5;

    if (maskgt[bm] <= 0.f) {                 // masked gt -> no candidates
        if (lane < TOPK) cand_idx[bm * TOPK + lane] = -1;
        return;
    }

    const float4 g = ((const float4*)gt)[bm];
    const float agt = (g.z - g.x) * (g.w - g.y);
    const float4* pdb = (const float4*)pd + (size_t)b * A_N;
    const int lbl = labels[bm];
    const float* scb = score + (size_t)b * A_N * C_N + lbl;

    // Analytic candidate ranges per stride, fixed up with the EXACT predicate
    // ((i+0.5f)*s vs edge, strict) so membership is bit-exact.
    int il0, nx0, jl0, ny0, il1, nx1, jl1, ny1, il2, nx2, jl2, ny2;
    int c0, c1, c2;
    {
#define RANGE(sv, nv, lo_out, cnt_out, e_lo, e_hi)                         \
        {                                                                  \
            int lo = (int)floorf(e_lo / sv - 0.5f) - 1; lo = max(lo, 0);   \
            while (lo < nv && !(((float)lo + 0.5f) * sv > e_lo)) ++lo;     \
            int hi = (int)ceilf(e_hi / sv - 0.5f) + 1; hi = min(hi, nv-1); \
            while (hi >= 0 && !(((float)hi + 0.5f) * sv < e_hi)) --hi;     \
            lo_out = lo; cnt_out = max(hi - lo + 1, 0);                    \
        }
        RANGE(8.f, 80, il0, nx0, g.x, g.z) RANGE(8.f, 80, jl0, ny0, g.y, g.w)
        RANGE(16.f, 40, il1, nx1, g.x, g.z) RANGE(16.f, 40, jl1, ny1, g.y, g.w)
        RANGE(32.f, 20, il2, nx2, g.x, g.z) RANGE(32.f, 20, jl2, ny2, g.y, g.w)
#undef RANGE
        c0 = nx0 * ny0; c1 = nx1 * ny1; c2 = nx2 * ny2;
    }
    const int T = c0 + c1 + c2;              // <= 305 for wh<=120

    // Enumerate candidates into registers (6 x 64 slots >= 305).
    unsigned long long keys[6];
    #pragma unroll
    for (int r = 0; r < 6; ++r) {
        keys[r] = 0ull;
        const int idx = r * 64 + lane;
        if (idx < T) {
            int q, n, gbase, il, jl, nx;
            if (idx < c0)           { q = idx;           n = 80; gbase = 0;    il = il0; jl = jl0; nx = nx0; }
            else if (idx < c0 + c1) { q = idx - c0;      n = 40; gbase = 6400; il = il1; jl = jl1; nx = nx1; }
            else                    { q = idx - c0 - c1; n = 20; gbase = 8000; il = il2; jl = jl2; nx = nx2; }
            const int row = q / nx, col = q - row * nx;
            const int a = gbase + (jl + row) * n + (il + col);
            float4 p = pdb[a];
            float apd = (p.z - p.x) * (p.w - p.y);
            float iou = iou_f(g, p, agt, apd);
            float sv = scb[(size_t)a * C_N];
            float i2 = iou * iou;
            float met = sv * i2 * i2 * i2;
            if (met > 0.f)
                keys[r] = ((unsigned long long)__float_as_uint(met) << 32)
                        | (unsigned)(~(unsigned)a);
        }
    }

    // 13 butterfly argmax passes (keys unique; 0 = empty).
    unsigned long long pick = 0ull;
    for (int k = 0; k < TOPK; ++k) {
        unsigned long long mx = 0ull;
        #pragma unroll
        for (int r = 0; r < 6; ++r) mx = umax64(mx, keys[r]);
        #pragma unroll
        for (int s = 32; s > 0; s >>= 1)
            mx = umax64(mx, (unsigned long long)__shfl_xor((long long)mx, s));
        if (mx == 0ull) break;               // uniform across wave
        if (lane == k) pick = mx;
        #pragma unroll
        for (int r = 0; r < 6; ++r) if (keys[r] == mx) keys[r] = 0ull;
    }

    // Positive picks occupy lanes 0..npos-1 contiguously; lane-local writes.
    if (lane < TOPK && pick) {
        const int a = (int)(~(unsigned)(pick & 0xFFFFFFFFu));
        const float v = __uint_as_float((unsigned)(pick >> 32));
        float4 p = pdb[a];
        float apd = (p.z - p.x) * (p.w - p.y);
        const int slot = bm * TOPK + lane;
        cand_idx[slot] = a; cand_met[slot] = v; cand_ov[slot] = iou_f(g, p, agt, apd);
    }

    const int npos = __popcll(__ballot(pick != 0ull));
    const int nfill = TOPK - npos;
    if (nfill > 0) {
        // top_k fills remaining slots with metric-0 entries at the LOWEST
        // global anchor indices; nfill>0 => npos<=12 => fill indices < 25,
        // and zeros among anchors 0..31 always number >= nfill.
        bool ing = false; float iou = 0.f, met = 0.f;
        if (lane < 32) {
            const float cx = ((float)lane + 0.5f) * 8.f, cy = 4.0f;
            ing = (cx > g.x) && (cy > g.y) && (cx < g.z) && (cy < g.w);
            if (ing) {
                float4 p = pdb[lane];
                float apd = (p.z - p.x) * (p.w - p.y);
                iou = iou_f(g, p, agt, apd);
                float i2 = iou * iou;
                met = scb[(size_t)lane * C_N] * i2 * i2 * i2;
            }
        }
        const bool z = (lane < 32) && !(met > 0.f);
        const unsigned zm32 = (unsigned)__ballot(z);   // zeros in lanes 0..31
        const int ingi = ing ? 1 : 0;

        // Owner-lane fill: lane L in [npos,TOPK) takes the (L-npos)'th zero.
        // The bit-scan and both shuffles run on ALL lanes (converged).
        int q = lane - npos; if (q < 0) q = 0;
        unsigned mm = zm32;
        for (int i = 0; i < q; ++i) mm &= mm - 1;
        const int aq = mm ? __builtin_ctz(mm) : 0;     // zero lane == anchor id
        const int f_ing = __shfl(ingi, aq);
        const float f_iou = __shfl(iou, aq);

        if (lane >= npos && lane < TOPK) {
            const int slot = bm * TOPK + lane;
            if (mm != 0u && f_ing) {         // picked by top_k AND in-gts
                cand_idx[slot] = aq; cand_met[slot] = 0.f; cand_ov[slot] = f_iou;
            } else {
                cand_idx[slot] = -1;
            }
        }
    }
}

// One block per batch: LDS claim counting, multi resolution (first-max over
// raw IoUs, all M), pos maxima, dense d_norm/d_info emission.
__global__ __launch_bounds__(256) void kB_resolve(
    const float* __restrict__ pd, const float* __restrict__ score,
    const int* __restrict__ labels, const float* __restrict__ gt,
    const int* __restrict__ cand_idx, const float* __restrict__ cand_met,
    const float* __restrict__ cand_ov,
    float* __restrict__ d_norm, unsigned* __restrict__ d_info)
{
    __shared__ unsigned s_cnt[A_N];          // 33.6 KB claim counts
    __shared__ int   s_sa[NSLOT];
    __shared__ float s_sm[NSLOT], s_so[NSLOT];
    __shared__ unsigned s_dd[(A_N + 31) / 32];
    __shared__ float s_pal[M_N], s_pov[M_N];
    __shared__ float4 s_gt[M_N];
    __shared__ int s_lb[M_N];
    __shared__ int s_ma[NSLOT], s_mm[NSLOT];
    __shared__ float s_mal[NSLOT], s_mov[NSLOT];
    __shared__ int s_mc;

    const int b = blockIdx.x;
    const int t = threadIdx.x;
    const size_t base = (size_t)b * A_N;

    for (int i = t; i < A_N; i += 256) s_cnt[i] = 0u;
    for (int i = t; i < (A_N + 31) / 32; i += 256) s_dd[i] = 0u;
    if (t < M_N) {
        s_gt[t] = ((const float4*)gt)[b * M_N + t];
        s_lb[t] = labels[b * M_N + t];
        s_pal[t] = 0.f; s_pov[t] = 0.f;
    }
    if (t == 0) s_mc = 0;
    for (int i = t; i < NSLOT; i += 256) {
        const int gi = b * NSLOT + i;
        s_sa[i] = cand_idx[gi]; s_sm[i] = cand_met[gi]; s_so[i] = cand_ov[gi];
    }
    __syncthreads();

    for (int i = t; i < NSLOT; i += 256) {
        const int a = s_sa[i];
        if (a >= 0) atomicAdd(&s_cnt[a], 1u);
    }
    __syncthreads();

    const float4* pdb = (const float4*)pd + base;
    for (int i = t; i < NSLOT; i += 256) {
        const int a = s_sa[i];
        if (a < 0) continue;
        if (s_cnt[a] == 1u) {
            const int m = i / TOPK;
            atomicMax((int*)&s_pal[m], __float_as_int(s_sm[i]));
            atomicMax((int*)&s_pov[m], __float_as_int(s_so[i]));
        } else {
            const unsigned bit = 1u << (a & 31);
            const unsigned old = atomicOr(&s_dd[a >> 5], bit);
            if (!(old & bit)) {              // one owner resolves this anchor
                float4 p = pdb[a];
                float apd = (p.z - p.x) * (p.w - p.y);
                float best = -1.f; int bmx = 0;
                #pragma unroll
                for (int mm = 0; mm < M_N; ++mm) {
                    float4 gg = s_gt[mm];
                    float agt = (gg.z - gg.x) * (gg.w - gg.y);
                    float iou = iou_f(gg, p, agt, apd);
                    if (iou > best) { best = iou; bmx = mm; }  // first max
                }
                const float sv = score[(base + a) * C_N + s_lb[bmx]];
                const float b2 = best * best;
                const float al = sv * b2 * b2 * b2;  // raw metric (no in_gts)
                const int s = atomicAdd(&s_mc, 1);
                s_ma[s] = a; s_mm[s] = bmx; s_mal[s] = al; s_mov[s] = best;
                atomicMax((int*)&s_pal[bmx], __float_as_int(al));
                atomicMax((int*)&s_pov[bmx], __float_as_int(best));
            }
        }
    }
    __syncthreads();

    // Dense defaults, then scattered overrides (barrier-separated).
    for (int i = t; i < A_N; i += 256) { d_norm[base + i] = 0.f; d_info[base + i] = 0u; }
    __syncthreads();
    for (int i = t; i < NSLOT; i += 256) {
        const int a = s_sa[i];
        if (a < 0 || s_cnt[a] != 1u) continue;
        const int m = i / TOPK;
        int l = s_lb[m]; if (l < 0) l = 0;
        d_norm[base + a] = s_sm[i] * s_pov[m] / (s_pal[m] + EPSF);
        d_info[base + a] = 0x80000000u | ((unsigned)m << 8) | (unsigned)l;
    }
    const int nm = s_mc;
    for (int i = t; i < nm; i += 256) {
        const int a = s_ma[i], m = s_mm[i];
        int l = s_lb[m]; if (l < 0) l = 0;
        d_norm[base + a] = s_mal[i] * s_pov[m] / (s_pal[m] + EPSF);
        d_info[base + a] = 0x80000000u | ((unsigned)m << 8) | (unsigned)l;
    }
}

// Streaming output writer. Reads dense d_info/d_norm, writes all outputs
// fully coalesced (score rows block-cooperatively as float4).
__global__ __launch_bounds__(256) void k_out(
    const int* __restrict__ labels, const float* __restrict__ gt,
    const float* __restrict__ d_norm, const unsigned* __restrict__ d_info,
    float* __restrict__ out)
{
    __shared__ float4 s_gt[M_N];
    __shared__ int s_l0;
    __shared__ int s_L[256];
    __shared__ float s_n[256];
    const int b = blockIdx.y;
    const int a0 = blockIdx.x * 256;
    const int t = threadIdx.x;
    const int a = a0 + t;
    if (t < M_N) s_gt[t] = ((const float4*)gt)[b * M_N + t];
    if (t == 0) { int l = labels[b * M_N]; s_l0 = (l < 0) ? 0 : l; }
    __syncthreads();

    float* out_lbl = out;
    float* out_box = out + (size_t)BS * A_N;
    float* out_sc  = out + (size_t)BS * A_N * 5;
    float* out_fg  = out + (size_t)BS * A_N * (5 + C_N);

    int L = -1; float nv = 0.f;
    if (a < A_N) {
        const size_t off = (size_t)b * A_N + a;
        const unsigned info = d_info[off];
        const int fg = (int)(info >> 31);
        const int m = fg ? (int)((info >> 8) & 255u) : 0;
        const int l = fg ? (int)(info & 255u) : s_l0;
        if (fg) { nv = d_norm[off]; L = l; }
        out_lbl[off] = (float)l;
        ((float4*)out_box)[off] = s_gt[m];
        out_fg[off] = fg ? 1.f : 0.f;
    }
    s_L[t] = L; s_n[t] = nv;
    __syncthreads();

    const int nA = min(256, A_N - a0);
    float4* dst = (float4*)(out_sc + ((size_t)b * A_N + a0) * C_N);
    const int total = nA * (C_N / 4);
    for (int i = t; i < total; i += 256) {
        const int al = i / (C_N / 4);
        const int c4 = (i % (C_N / 4)) * 4;
        const int Lv = s_L[al];
        float4 v = make_float4(0.f, 0.f, 0.f, 0.f);
        if (Lv >= c4 && Lv < c4 + 4) ((float*)&v)[Lv - c4] = s_n[al];
        dst[i] = v;
    }
}

extern "C" void kernel_launch(void* const* d_in, const int* in_sizes, int n_in,
                              void* d_out, int out_size, void* d_ws, size_t ws_size,
                              hipStream_t stream) {
    const float* pd      = (const float*)d_in[0];
    const float* score   = (const float*)d_in[1];
    const int*   labels  = (const int*)d_in[3];
    const float* gt      = (const float*)d_in[4];
    const float* maskgt  = (const float*)d_in[5];
    float* out = (float*)d_out;

    const size_t nBA = (size_t)BS * A_N;
    const int NS = BS * NSLOT;               // 13312
    float*    d_norm  = (float*)d_ws;
    unsigned* d_info  = (unsigned*)(d_norm + nBA);
    int*      cand_idx = (int*)(d_info + nBA);
    float*    cand_met = (float*)(cand_idx + NS);
    float*    cand_ov  = cand_met + NS;
    (void)ws_size; (void)in_sizes; (void)n_in;

    kA_topk<<<BS * M_N / 4, 256, 0, stream>>>(pd, score, labels, gt, maskgt,
        cand_idx, cand_met, cand_ov);
    kB_resolve<<<BS, 256, 0, stream>>>(pd, score, labels, gt,
        cand_idx, cand_met, cand_ov, d_norm, d_info);
    k_out<<<dim3((A_N + 255) / 256, BS), 256, 0, stream>>>(labels, gt, d_norm, d_info, out);
}

// Round 9
// 68.663 us; speedup vs baseline: 1.1819x; 1.0516x over previous
//
#include <hip/hip_runtime.h>

// TaskAlignedAssigner (YOLO TAL) for bs=32, A=8400, M=32, C=80, K=13.
// Outputs (concat, float32): labels [b,A], boxes [b,A,4], scores [b,A,80], fg [b,A].
// 2-kernel design:
//   kA_topk      : 256 blocks, one WAVE per gt -> 13 compact candidate slots/gt
//   k_resolve_out: 33x32 blocks; per-block in-LDS batch resolution (bitmaps,
//                  pos maxima, multi-gt first-max) + direct coalesced output.

#define BS 32
#define A_N 8400
#define M_N 32
#define C_N 80
#define TOPK 13
#define EPSF 1e-9f
#define NSLOT (M_N * TOPK)     // 416 slots per batch
#define NW ((A_N + 31) / 32)   // 263 bitmap words

__device__ __forceinline__ float iou_f(float4 g, float4 p, float agt, float apd) {
    float lx = fmaxf(g.x, p.x), ly = fmaxf(g.y, p.y);
    float rx = fminf(g.z, p.z), ry = fminf(g.w, p.w);
    float w = fmaxf(rx - lx, 0.f), h = fmaxf(ry - ly, 0.f);
    float inter = w * h;
    return inter / (agt + apd - inter + EPSF);
}

__device__ __forceinline__ unsigned long long umax64(unsigned long long a, unsigned long long b) {
    return a > b ? a : b;
}

// One WAVE per (b,m). Candidate set = 3 analytic grid rectangles (exact via
// strict-compare fixup). Top-13 via butterfly argmax over packed u64 keys
// (value desc, index asc == jax.lax.top_k tie order), then zero-fill picks at
// lowest global indices. Each of the 13 slots has exactly ONE writer lane;
// all __shfl reads are executed by all 64 lanes. (Identical to the passing R8.)
__global__ __launch_bounds__(256) void kA_topk(
    const float* __restrict__ pd, const float* __restrict__ score,
    const int* __restrict__ labels, const float* __restrict__ gt,
    const float* __restrict__ maskgt,
    int* __restrict__ cand_idx, float* __restrict__ cand_met,
    float* __restrict__ cand_ov)
{
    const int wave = threadIdx.x >> 6;
    const int lane = threadIdx.x & 63;
    const int bm = blockIdx.x * 4 + wave;
    const int b = bm >> 5;

    if (maskgt[bm] <= 0.f) {                 // masked gt -> no candidates
        if (lane < TOPK) cand_idx[bm * TOPK + lane] = -1;
        return;
    }

    const float4 g = ((const float4*)gt)[bm];
    const float agt = (g.z - g.x) * (g.w - g.y);
    const float4* pdb = (const float4*)pd + (size_t)b * A_N;
    const int lbl = labels[bm];
    const float* scb = score + (size_t)b * A_N * C_N + lbl;

    // Analytic candidate ranges per stride, fixed up with the EXACT predicate
    // ((i+0.5f)*s vs edge, strict) so membership is bit-exact.
    int il0, nx0, jl0, ny0, il1, nx1, jl1, ny1, il2, nx2, jl2, ny2;
    int c0, c1, c2;
    {
#define RANGE(sv, nv, lo_out, cnt_out, e_lo, e_hi)                         \
        {                                                                  \
            int lo = (int)floorf(e_lo / sv - 0.5f) - 1; lo = max(lo, 0);   \
            while (lo < nv && !(((float)lo + 0.5f) * sv > e_lo)) ++lo;     \
            int hi = (int)ceilf(e_hi / sv - 0.5f) + 1; hi = min(hi, nv-1); \
            while (hi >= 0 && !(((float)hi + 0.5f) * sv < e_hi)) --hi;     \
            lo_out = lo; cnt_out = max(hi - lo + 1, 0);                    \
        }
        RANGE(8.f, 80, il0, nx0, g.x, g.z) RANGE(8.f, 80, jl0, ny0, g.y, g.w)
        RANGE(16.f, 40, il1, nx1, g.x, g.z) RANGE(16.f, 40, jl1, ny1, g.y, g.w)
        RANGE(32.f, 20, il2, nx2, g.x, g.z) RANGE(32.f, 20, jl2, ny2, g.y, g.w)
#undef RANGE
        c0 = nx0 * ny0; c1 = nx1 * ny1; c2 = nx2 * ny2;
    }
    const int T = c0 + c1 + c2;              // <= 305 for wh<=120

    unsigned long long keys[6];
    #pragma unroll
    for (int r = 0; r < 6; ++r) {
        keys[r] = 0ull;
        const int idx = r * 64 + lane;
        if (idx < T) {
            int q, n, gbase, il, jl, nx;
            if (idx < c0)           { q = idx;           n = 80; gbase = 0;    il = il0; jl = jl0; nx = nx0; }
            else if (idx < c0 + c1) { q = idx - c0;      n = 40; gbase = 6400; il = il1; jl = jl1; nx = nx1; }
            else                    { q = idx - c0 - c1; n = 20; gbase = 8000; il = il2; jl = jl2; nx = nx2; }
            const int row = q / nx, col = q - row * nx;
            const int a = gbase + (jl + row) * n + (il + col);
            float4 p = pdb[a];
            float apd = (p.z - p.x) * (p.w - p.y);
            float iou = iou_f(g, p, agt, apd);
            float sv = scb[(size_t)a * C_N];
            float i2 = iou * iou;
            float met = sv * i2 * i2 * i2;
            if (met > 0.f)
                keys[r] = ((unsigned long long)__float_as_uint(met) << 32)
                        | (unsigned)(~(unsigned)a);
        }
    }

    // 13 butterfly argmax passes (keys unique; 0 = empty).
    unsigned long long pick = 0ull;
    for (int k = 0; k < TOPK; ++k) {
        unsigned long long mx = 0ull;
        #pragma unroll
        for (int r = 0; r < 6; ++r) mx = umax64(mx, keys[r]);
        #pragma unroll
        for (int s = 32; s > 0; s >>= 1)
            mx = umax64(mx, (unsigned long long)__shfl_xor((long long)mx, s));
        if (mx == 0ull) break;               // uniform across wave
        if (lane == k) pick = mx;
        #pragma unroll
        for (int r = 0; r < 6; ++r) if (keys[r] == mx) keys[r] = 0ull;
    }

    // Positive picks occupy lanes 0..npos-1 contiguously; lane-local writes.
    if (lane < TOPK && pick) {
        const int a = (int)(~(unsigned)(pick & 0xFFFFFFFFu));
        const float v = __uint_as_float((unsigned)(pick >> 32));
        float4 p = pdb[a];
        float apd = (p.z - p.x) * (p.w - p.y);
        const int slot = bm * TOPK + lane;
        cand_idx[slot] = a; cand_met[slot] = v; cand_ov[slot] = iou_f(g, p, agt, apd);
    }

    const int npos = __popcll(__ballot(pick != 0ull));
    const int nfill = TOPK - npos;
    if (nfill > 0) {
        // top_k fills remaining slots with metric-0 entries at the LOWEST
        // global anchor indices; nfill>0 => npos<=12 => fill indices < 25.
        bool ing = false; float iou = 0.f, met = 0.f;
        if (lane < 32) {
            const float cx = ((float)lane + 0.5f) * 8.f, cy = 4.0f;
            ing = (cx > g.x) && (cy > g.y) && (cx < g.z) && (cy < g.w);
            if (ing) {
                float4 p = pdb[lane];
                float apd = (p.z - p.x) * (p.w - p.y);
                iou = iou_f(g, p, agt, apd);
                float i2 = iou * iou;
                met = scb[(size_t)lane * C_N] * i2 * i2 * i2;
            }
        }
        const bool z = (lane < 32) && !(met > 0.f);
        const unsigned zm32 = (unsigned)__ballot(z);   // zeros in lanes 0..31
        const int ingi = ing ? 1 : 0;

        // Owner-lane fill: lane L in [npos,TOPK) takes the (L-npos)'th zero.
        // Bit-scan and shuffles run on ALL lanes (converged).
        int q = lane - npos; if (q < 0) q = 0;
        unsigned mm = zm32;
        for (int i = 0; i < q; ++i) mm &= mm - 1;
        const int aq = mm ? __builtin_ctz(mm) : 0;     // zero lane == anchor id
        const int f_ing = __shfl(ingi, aq);
        const float f_iou = __shfl(iou, aq);

        if (lane >= npos && lane < TOPK) {
            const int slot = bm * TOPK + lane;
            if (mm != 0u && f_ing) {         // picked by top_k AND in-gts
                cand_idx[slot] = aq; cand_met[slot] = 0.f; cand_ov[slot] = f_iou;
            } else {
                cand_idx[slot] = -1;
            }
        }
    }
}

// Fused resolution + output. Grid (33, BS); block handles anchors
// [a0, a0+256) of batch b, but resolves the WHOLE batch in LDS (cheap:
// bitmaps + 416 slots) so pos maxima are complete. Multi-claimed anchors
// resolved deterministically (first-max over raw IoUs, all M) — identical
// result in every block that touches them.
__global__ __launch_bounds__(256) void k_resolve_out(
    const float* __restrict__ pd, const float* __restrict__ score,
    const int* __restrict__ labels, const float* __restrict__ gt,
    const int* __restrict__ cand_idx, const float* __restrict__ cand_met,
    const float* __restrict__ cand_ov,
    float* __restrict__ out)
{
    __shared__ int   s_sa[NSLOT];
    __shared__ float s_sm[NSLOT], s_so[NSLOT];
    __shared__ unsigned s_claim[NW], s_multi[NW], s_own[NW];
    __shared__ float4 s_gt[M_N];
    __shared__ int s_lb[M_N];
    __shared__ float s_pal[M_N], s_pov[M_N];
    __shared__ int   s_am[256];      // in-range single-claim: m
    __shared__ float s_av[256];      // in-range single-claim: met
    __shared__ int   s_L[256];
    __shared__ float s_n[256];

    const int b = blockIdx.y;
    const int a0 = blockIdx.x * 256;
    const int t = threadIdx.x;
    const size_t base = (size_t)b * A_N;
    const float4* pdb = (const float4*)pd + base;

    // Init + loads.
    for (int i = t; i < NW; i += 256) { s_claim[i] = 0u; s_multi[i] = 0u; s_own[i] = 0u; }
    if (t < M_N) {
        s_gt[t] = ((const float4*)gt)[b * M_N + t];
        s_lb[t] = labels[b * M_N + t];
        s_pal[t] = 0.f; s_pov[t] = 0.f;
    }
    for (int i = t; i < NSLOT; i += 256) {
        const int gi = b * NSLOT + i;
        s_sa[i] = cand_idx[gi]; s_sm[i] = cand_met[gi]; s_so[i] = cand_ov[gi];
    }
    s_am[t] = 0; s_av[t] = 0.f;
    __syncthreads();

    // Claim pass: mark claimed / multi.
    for (int i = t; i < NSLOT; i += 256) {
        const int a = s_sa[i];
        if (a < 0) continue;
        const unsigned bit = 1u << (a & 31);
        const unsigned old = atomicOr(&s_claim[a >> 5], bit);
        if (old & bit) atomicOr(&s_multi[a >> 5], bit);
    }
    __syncthreads();

    // Pos pass: singles feed pal/pov (+ in-range scatter); one owner per
    // multi anchor resolves and feeds pal/pov.
    for (int i = t; i < NSLOT; i += 256) {
        const int a = s_sa[i];
        if (a < 0) continue;
        const unsigned bit = 1u << (a & 31);
        if (!(s_multi[a >> 5] & bit)) {      // single claim
            const int m = i / TOPK;
            atomicMax((int*)&s_pal[m], __float_as_int(s_sm[i]));
            atomicMax((int*)&s_pov[m], __float_as_int(s_so[i]));
            const int la = a - a0;
            if (la >= 0 && la < 256) { s_am[la] = m; s_av[la] = s_sm[i]; }
        } else {
            const unsigned oo = atomicOr(&s_own[a >> 5], bit);
            if (!(oo & bit)) {               // this slot resolves the anchor
                float4 p = pdb[a];
                float apd = (p.z - p.x) * (p.w - p.y);
                float best = -1.f; int bmx = 0;
                #pragma unroll
                for (int mm = 0; mm < M_N; ++mm) {
                    float4 gg = s_gt[mm];
                    float agt = (gg.z - gg.x) * (gg.w - gg.y);
                    float iou = iou_f(gg, p, agt, apd);
                    if (iou > best) { best = iou; bmx = mm; }  // first max
                }
                const float sv = score[(base + a) * C_N + s_lb[bmx]];
                const float b2 = best * best;
                const float al = sv * b2 * b2 * b2;  // raw metric (no in_gts)
                atomicMax((int*)&s_pal[bmx], __float_as_int(al));
                atomicMax((int*)&s_pov[bmx], __float_as_int(best));
            }
        }
    }
    __syncthreads();

    // Output pass.
    float* out_lbl = out;
    float* out_box = out + (size_t)BS * A_N;
    float* out_sc  = out + (size_t)BS * A_N * 5;
    float* out_fg  = out + (size_t)BS * A_N * (5 + C_N);

    const int a = a0 + t;
    int L = -1; float nv = 0.f;
    if (a < A_N) {
        const unsigned bit = 1u << (a & 31);
        const bool cl = (s_claim[a >> 5] & bit) != 0u;
        const bool mu = (s_multi[a >> 5] & bit) != 0u;
        int m_out = 0;
        if (cl && !mu) {                     // single claim
            m_out = s_am[t];
            const int pm = m_out;
            nv = s_av[t] * s_pov[pm] / (s_pal[pm] + EPSF);
        } else if (mu) {                     // multi: recompute (deterministic)
            float4 p = pdb[a];
            float apd = (p.z - p.x) * (p.w - p.y);
            float best = -1.f; int bmx = 0;
            #pragma unroll
            for (int mm = 0; mm < M_N; ++mm) {
                float4 gg = s_gt[mm];
                float agt = (gg.z - gg.x) * (gg.w - gg.y);
                float iou = iou_f(gg, p, agt, apd);
                if (iou > best) { best = iou; bmx = mm; }
            }
            const float sv = score[(base + a) * C_N + s_lb[bmx]];
            const float b2 = best * best;
            const float al = sv * b2 * b2 * b2;
            m_out = bmx;
            nv = al * s_pov[bmx] / (s_pal[bmx] + EPSF);
        }
        int l = s_lb[m_out]; if (l < 0) l = 0;
        if (cl) L = l;                       // one-hot target only for fg
        out_lbl[base + a] = (float)l;
        ((float4*)out_box)[base + a] = s_gt[m_out];
        out_fg[base + a] = cl ? 1.f : 0.f;
        if (!cl) nv = 0.f;
    }
    s_L[t] = L; s_n[t] = nv;
    __syncthreads();

    const int nA = min(256, A_N - a0);
    float4* dst = (float4*)(out_sc + (base + a0) * C_N);
    const int total = nA * (C_N / 4);
    for (int i = t; i < total; i += 256) {
        const int al = i / (C_N / 4);
        const int c4 = (i % (C_N / 4)) * 4;
        const int Lv = s_L[al];
        float4 v = make_float4(0.f, 0.f, 0.f, 0.f);
        if (Lv >= c4 && Lv < c4 + 4) ((float*)&v)[Lv - c4] = s_n[al];
        dst[i] = v;
    }
}

extern "C" void kernel_launch(void* const* d_in, const int* in_sizes, int n_in,
                              void* d_out, int out_size, void* d_ws, size_t ws_size,
                              hipStream_t stream) {
    const float* pd      = (const float*)d_in[0];
    const float* score   = (const float*)d_in[1];
    const int*   labels  = (const int*)d_in[3];
    const float* gt      = (const float*)d_in[4];
    const float* maskgt  = (const float*)d_in[5];
    float* out = (float*)d_out;

    const int NS = BS * NSLOT;               // 13312
    int*   cand_idx = (int*)d_ws;
    float* cand_met = (float*)(cand_idx + NS);
    float* cand_ov  = cand_met + NS;
    (void)ws_size; (void)in_sizes; (void)n_in;

    kA_topk<<<BS * M_N / 4, 256, 0, stream>>>(pd, score, labels, gt, maskgt,
        cand_idx, cand_met, cand_ov);
    k_resolve_out<<<dim3((A_N + 255) / 256, BS), 256, 0, stream>>>(pd, score,
        labels, gt, cand_idx, cand_met, cand_ov, out);
}

// Round 10
// 51.425 us; speedup vs baseline: 1.5781x; 1.3352x over previous
//
#include <hip/hip_runtime.h>

// TaskAlignedAssigner (YOLO TAL) for bs=32, A=8400, M=32, C=80, K=13.
// Outputs (concat, float32): labels [b,A], boxes [b,A,4], scores [b,A,80], fg [b,A].
// 3-kernel design:
//   kA_topk   : 256 blocks, one WAVE per gt -> 13 compact candidate slots/gt
//   kB_resolve: 32 blocks (one per batch) -> LDS claim counting + multi-gt
//               resolution + pos maxima -> dense packed d_meta[b,a]
//   kC_write  : fillBuffer-shaped streaming writer (4463 tiny blocks, low
//               VGPR, no barriers) -> all 93 MB of outputs near write BW.

#define BS 32
#define A_N 8400
#define M_N 32
#define C_N 80
#define TOPK 13
#define EPSF 1e-9f
#define NSLOT (M_N * TOPK)     // 416 slots per batch
#define NW ((A_N + 31) / 32)
#define NBA (BS * A_N)         // 268800
#define SCORE_BLKS 4200        // 5,376,000 f4 / 1280 per block
#define REST_BLKS 263          // ceil(268800 / 1024)

__device__ __forceinline__ float iou_f(float4 g, float4 p, float agt, float apd) {
    float lx = fmaxf(g.x, p.x), ly = fmaxf(g.y, p.y);
    float rx = fminf(g.z, p.z), ry = fminf(g.w, p.w);
    float w = fmaxf(rx - lx, 0.f), h = fmaxf(ry - ly, 0.f);
    float inter = w * h;
    return inter / (agt + apd - inter + EPSF);
}

__device__ __forceinline__ unsigned long long umax64(unsigned long long a, unsigned long long b) {
    return a > b ? a : b;
}

// One WAVE per (b,m). Identical to the passing R8/R9 kernel.
__global__ __launch_bounds__(256) void kA_topk(
    const float* __restrict__ pd, const float* __restrict__ score,
    const int* __restrict__ labels, const float* __restrict__ gt,
    const float* __restrict__ maskgt,
    int* __restrict__ cand_idx, float* __restrict__ cand_met,
    float* __restrict__ cand_ov)
{
    const int wave = threadIdx.x >> 6;
    const int lane = threadIdx.x & 63;
    const int bm = blockIdx.x * 4 + wave;
    const int b = bm >> 5;

    if (maskgt[bm] <= 0.f) {                 // masked gt -> no candidates
        if (lane < TOPK) cand_idx[bm * TOPK + lane] = -1;
        return;
    }

    const float4 g = ((const float4*)gt)[bm];
    const float agt = (g.z - g.x) * (g.w - g.y);
    const float4* pdb = (const float4*)pd + (size_t)b * A_N;
    const int lbl = labels[bm];
    const float* scb = score + (size_t)b * A_N * C_N + lbl;

    int il0, nx0, jl0, ny0, il1, nx1, jl1, ny1, il2, nx2, jl2, ny2;
    int c0, c1, c2;
    {
#define RANGE(sv, nv, lo_out, cnt_out, e_lo, e_hi)                         \
        {                                                                  \
            int lo = (int)floorf(e_lo / sv - 0.5f) - 1; lo = max(lo, 0);   \
            while (lo < nv && !(((float)lo + 0.5f) * sv > e_lo)) ++lo;     \
            int hi = (int)ceilf(e_hi / sv - 0.5f) + 1; hi = min(hi, nv-1); \
            while (hi >= 0 && !(((float)hi + 0.5f) * sv < e_hi)) --hi;     \
            lo_out = lo; cnt_out = max(hi - lo + 1, 0);                    \
        }
        RANGE(8.f, 80, il0, nx0, g.x, g.z) RANGE(8.f, 80, jl0, ny0, g.y, g.w)
        RANGE(16.f, 40, il1, nx1, g.x, g.z) RANGE(16.f, 40, jl1, ny1, g.y, g.w)
        RANGE(32.f, 20, il2, nx2, g.x, g.z) RANGE(32.f, 20, jl2, ny2, g.y, g.w)
#undef RANGE
        c0 = nx0 * ny0; c1 = nx1 * ny1; c2 = nx2 * ny2;
    }
    const int T = c0 + c1 + c2;              // <= 305 for wh<=120

    unsigned long long keys[6];
    #pragma unroll
    for (int r = 0; r < 6; ++r) {
        keys[r] = 0ull;
        const int idx = r * 64 + lane;
        if (idx < T) {
            int q, n, gbase, il, jl, nx;
            if (idx < c0)           { q = idx;           n = 80; gbase = 0;    il = il0; jl = jl0; nx = nx0; }
            else if (idx < c0 + c1) { q = idx - c0;      n = 40; gbase = 6400; il = il1; jl = jl1; nx = nx1; }
            else                    { q = idx - c0 - c1; n = 20; gbase = 8000; il = il2; jl = jl2; nx = nx2; }
            const int row = q / nx, col = q - row * nx;
            const int a = gbase + (jl + row) * n + (il + col);
            float4 p = pdb[a];
            float apd = (p.z - p.x) * (p.w - p.y);
            float iou = iou_f(g, p, agt, apd);
            float sv = scb[(size_t)a * C_N];
            float i2 = iou * iou;
            float met = sv * i2 * i2 * i2;
            if (met > 0.f)
                keys[r] = ((unsigned long long)__float_as_uint(met) << 32)
                        | (unsigned)(~(unsigned)a);
        }
    }

    unsigned long long pick = 0ull;
    for (int k = 0; k < TOPK; ++k) {
        unsigned long long mx = 0ull;
        #pragma unroll
        for (int r = 0; r < 6; ++r) mx = umax64(mx, keys[r]);
        #pragma unroll
        for (int s = 32; s > 0; s >>= 1)
            mx = umax64(mx, (unsigned long long)__shfl_xor((long long)mx, s));
        if (mx == 0ull) break;               // uniform across wave
        if (lane == k) pick = mx;
        #pragma unroll
        for (int r = 0; r < 6; ++r) if (keys[r] == mx) keys[r] = 0ull;
    }

    if (lane < TOPK && pick) {
        const int a = (int)(~(unsigned)(pick & 0xFFFFFFFFu));
        const float v = __uint_as_float((unsigned)(pick >> 32));
        float4 p = pdb[a];
        float apd = (p.z - p.x) * (p.w - p.y);
        const int slot = bm * TOPK + lane;
        cand_idx[slot] = a; cand_met[slot] = v; cand_ov[slot] = iou_f(g, p, agt, apd);
    }

    const int npos = __popcll(__ballot(pick != 0ull));
    const int nfill = TOPK - npos;
    if (nfill > 0) {
        bool ing = false; float iou = 0.f, met = 0.f;
        if (lane < 32) {
            const float cx = ((float)lane + 0.5f) * 8.f, cy = 4.0f;
            ing = (cx > g.x) && (cy > g.y) && (cx < g.z) && (cy < g.w);
            if (ing) {
                float4 p = pdb[lane];
                float apd = (p.z - p.x) * (p.w - p.y);
                iou = iou_f(g, p, agt, apd);
                float i2 = iou * iou;
                met = scb[(size_t)lane * C_N] * i2 * i2 * i2;
            }
        }
        const bool z = (lane < 32) && !(met > 0.f);
        const unsigned zm32 = (unsigned)__ballot(z);
        const int ingi = ing ? 1 : 0;

        int q = lane - npos; if (q < 0) q = 0;
        unsigned mm = zm32;
        for (int i = 0; i < q; ++i) mm &= mm - 1;
        const int aq = mm ? __builtin_ctz(mm) : 0;
        const int f_ing = __shfl(ingi, aq);
        const float f_iou = __shfl(iou, aq);

        if (lane >= npos && lane < TOPK) {
            const int slot = bm * TOPK + lane;
            if (mm != 0u && f_ing) {
                cand_idx[slot] = aq; cand_met[slot] = 0.f; cand_ov[slot] = f_iou;
            } else {
                cand_idx[slot] = -1;
            }
        }
    }
}

// One block per batch: LDS claim counting, multi resolution (first-max over
// raw IoUs, all M), pos maxima, dense packed d_meta emission.
// meta.x: bit31 fg, bits8-15 m, bits0-7 label(clamped); meta.y: norm bits.
__global__ __launch_bounds__(256) void kB_resolve(
    const float* __restrict__ pd, const float* __restrict__ score,
    const int* __restrict__ labels, const float* __restrict__ gt,
    const int* __restrict__ cand_idx, const float* __restrict__ cand_met,
    const float* __restrict__ cand_ov,
    uint2* __restrict__ d_meta)
{
    __shared__ unsigned s_cnt[A_N];          // 33.6 KB claim counts
    __shared__ int   s_sa[NSLOT];
    __shared__ float s_sm[NSLOT], s_so[NSLOT];
    __shared__ unsigned s_dd[NW];
    __shared__ float s_pal[M_N], s_pov[M_N];
    __shared__ float4 s_gt[M_N];
    __shared__ int s_lb[M_N];
    __shared__ int s_ma[NSLOT], s_mm[NSLOT];
    __shared__ float s_mal[NSLOT];
    __shared__ int s_mc;

    const int b = blockIdx.x;
    const int t = threadIdx.x;
    const size_t base = (size_t)b * A_N;

    for (int i = t; i < A_N; i += 256) s_cnt[i] = 0u;
    for (int i = t; i < NW; i += 256) s_dd[i] = 0u;
    if (t < M_N) {
        s_gt[t] = ((const float4*)gt)[b * M_N + t];
        s_lb[t] = labels[b * M_N + t];
        s_pal[t] = 0.f; s_pov[t] = 0.f;
    }
    if (t == 0) s_mc = 0;
    for (int i = t; i < NSLOT; i += 256) {
        const int gi = b * NSLOT + i;
        s_sa[i] = cand_idx[gi]; s_sm[i] = cand_met[gi]; s_so[i] = cand_ov[gi];
    }
    __syncthreads();

    for (int i = t; i < NSLOT; i += 256) {
        const int a = s_sa[i];
        if (a >= 0) atomicAdd(&s_cnt[a], 1u);
    }
    __syncthreads();

    const float4* pdb = (const float4*)pd + base;
    for (int i = t; i < NSLOT; i += 256) {
        const int a = s_sa[i];
        if (a < 0) continue;
        if (s_cnt[a] == 1u) {
            const int m = i / TOPK;
            atomicMax((int*)&s_pal[m], __float_as_int(s_sm[i]));
            atomicMax((int*)&s_pov[m], __float_as_int(s_so[i]));
        } else {
            const unsigned bit = 1u << (a & 31);
            const unsigned old = atomicOr(&s_dd[a >> 5], bit);
            if (!(old & bit)) {              // one owner resolves this anchor
                float4 p = pdb[a];
                float apd = (p.z - p.x) * (p.w - p.y);
                float best = -1.f; int bmx = 0;
                #pragma unroll
                for (int mm = 0; mm < M_N; ++mm) {
                    float4 gg = s_gt[mm];
                    float agt = (gg.z - gg.x) * (gg.w - gg.y);
                    float iou = iou_f(gg, p, agt, apd);
                    if (iou > best) { best = iou; bmx = mm; }  // first max
                }
                const float sv = score[(base + a) * C_N + s_lb[bmx]];
                const float b2 = best * best;
                const float al = sv * b2 * b2 * b2;  // raw metric (no in_gts)
                const int s = atomicAdd(&s_mc, 1);
                s_ma[s] = a; s_mm[s] = bmx; s_mal[s] = al;
                atomicMax((int*)&s_pal[bmx], __float_as_int(al));
                atomicMax((int*)&s_pov[bmx], __float_as_int(best));
            }
        }
    }
    __syncthreads();

    // Dense defaults, then scattered overrides (barrier-separated;
    // singles and multis touch disjoint anchors).
    for (int i = t; i < A_N; i += 256) d_meta[base + i] = make_uint2(0u, 0u);
    __syncthreads();
    for (int i = t; i < NSLOT; i += 256) {
        const int a = s_sa[i];
        if (a < 0 || s_cnt[a] != 1u) continue;
        const int m = i / TOPK;
        int l = s_lb[m]; if (l < 0) l = 0;
        const float nv = s_sm[i] * s_pov[m] / (s_pal[m] + EPSF);
        d_meta[base + a] = make_uint2(0x80000000u | ((unsigned)m << 8) | (unsigned)l,
                                      __float_as_uint(nv));
    }
    const int nm = s_mc;
    for (int i = t; i < nm; i += 256) {
        const int a = s_ma[i], m = s_mm[i];
        int l = s_lb[m]; if (l < 0) l = 0;
        const float nv = s_mal[i] * s_pov[m] / (s_pal[m] + EPSF);
        d_meta[base + a] = make_uint2(0x80000000u | ((unsigned)m << 8) | (unsigned)l,
                                      __float_as_uint(nv));
    }
}

// Streaming writer: fillBuffer-shaped. Score region written f4-linear with
// static compare-select one-hot (no dynamic vector indexing); meta reads are
// L1-broadcast. Rest path writes lbl/box/fg.
__global__ __launch_bounds__(256) void kC_write(
    const int* __restrict__ labels, const float* __restrict__ gt,
    const uint2* __restrict__ d_meta, float* __restrict__ out)
{
    const int t = threadIdx.x;
    float* out_lbl = out;
    float* out_box = out + (size_t)NBA;
    float* out_sc  = out + (size_t)NBA * 5;
    float* out_fg  = out + (size_t)NBA * (5 + C_N);

    if (blockIdx.x < SCORE_BLKS) {
        const unsigned base = (unsigned)blockIdx.x * 1280u;
        float4* dst = (float4*)out_sc;
        #pragma unroll
        for (int it = 0; it < 5; ++it) {
            const unsigned idx = base + (unsigned)it * 256u + (unsigned)t;
            const unsigned a = idx / 20u;              // global anchor (b*A_N+a)
            const int c4 = (int)(idx - a * 20u) * 4;
            const uint2 mt = d_meta[a];
            const float n = __uint_as_float(mt.y);
            const int L = (mt.x & 0x80000000u) ? (int)(mt.x & 255u) : -1;
            float4 v;
            v.x = (L == c4)     ? n : 0.f;
            v.y = (L == c4 + 1) ? n : 0.f;
            v.z = (L == c4 + 2) ? n : 0.f;
            v.w = (L == c4 + 3) ? n : 0.f;
            dst[idx] = v;
        }
    } else {
        const unsigned rb = (unsigned)blockIdx.x - SCORE_BLKS;
        #pragma unroll
        for (int it = 0; it < 4; ++it) {
            const unsigned a = rb * 1024u + (unsigned)it * 256u + (unsigned)t;
            if (a < (unsigned)NBA) {
                const unsigned b = a / (unsigned)A_N;
                const uint2 mt = d_meta[a];
                const bool fg = (mt.x & 0x80000000u) != 0u;
                const int m = fg ? (int)((mt.x >> 8) & 255u) : 0;
                int l;
                if (fg) l = (int)(mt.x & 255u);
                else { l = labels[b * M_N]; if (l < 0) l = 0; }
                out_lbl[a] = (float)l;
                ((float4*)out_box)[a] = ((const float4*)gt)[b * M_N + m];
                out_fg[a] = fg ? 1.f : 0.f;
            }
        }
    }
}

extern "C" void kernel_launch(void* const* d_in, const int* in_sizes, int n_in,
                              void* d_out, int out_size, void* d_ws, size_t ws_size,
                              hipStream_t stream) {
    const float* pd      = (const float*)d_in[0];
    const float* score   = (const float*)d_in[1];
    const int*   labels  = (const int*)d_in[3];
    const float* gt      = (const float*)d_in[4];
    const float* maskgt  = (const float*)d_in[5];
    float* out = (float*)d_out;

    const int NS = BS * NSLOT;               // 13312
    uint2* d_meta  = (uint2*)d_ws;
    int*   cand_idx = (int*)(d_meta + NBA);
    float* cand_met = (float*)(cand_idx + NS);
    float* cand_ov  = cand_met + NS;
    (void)ws_size; (void)in_sizes; (void)n_in;

    kA_topk<<<BS * M_N / 4, 256, 0, stream>>>(pd, score, labels, gt, maskgt,
        cand_idx, cand_met, cand_ov);
    kB_resolve<<<BS, 256, 0, stream>>>(pd, score, labels, gt,
        cand_idx, cand_met, cand_ov, d_meta);
    kC_write<<<SCORE_BLKS + REST_BLKS, 256, 0, stream>>>(labels, gt, d_meta, out);
}